// Round 11
// baseline (445.795 us; speedup 1.0000x reference)
//
#include <hip/hip_runtime.h>
#include <hip/hip_bf16.h>

// Attention_aux: fused aux-attention scorer + context + output projection.
// PATH A (ws >= 216.7 MB):
//   convw1 (W1->bf16), convenc (enc->bf16, 201MB; grid FIXED to 49152),
//   hbias,
//   gemm8: m201-faithful 256x256 BK=64 GEMM, gload_lds BOTH operands,
//          A triple-buf + B double-buf (160KB LDS exactly), 4 phases/K-tile
//          of 16 MFMA, counted vmcnt(4)/tile (never 0 mid-loop), raw
//          barriers, setprio, 0-conflict XOR-8 LDS geometry (rule 21).
//   softmax, ctxpart_bf (bf16 enc), ctxreduce, final.
// PATH B (fallback, small ws): R9 pipeline verbatim (~415us).

typedef float          fx4 __attribute__((ext_vector_type(4)));
typedef short          sv8 __attribute__((ext_vector_type(8)));
typedef unsigned short uv4 __attribute__((ext_vector_type(4)));
typedef unsigned int   ui4 __attribute__((ext_vector_type(4)));

__device__ __forceinline__ unsigned short f2bf(float x) {
  unsigned u = __float_as_uint(x);
  return (unsigned short)((u + 0x7FFFu + ((u >> 16) & 1u)) >> 16);
}
__device__ __forceinline__ unsigned cvtpk(float lo, float hi) {
  unsigned r;
  asm("v_cvt_pk_bf16_f32 %0, %1, %2" : "=v"(r) : "v"(lo), "v"(hi));
  return r;
}
__device__ __forceinline__ ui4 pack8(fx4 a, fx4 b) {
  ui4 v;
  v[0] = cvtpk(a[0], a[1]); v[1] = cvtpk(a[2], a[3]);
  v[2] = cvtpk(b[0], b[1]); v[3] = cvtpk(b[2], b[3]);
  return v;
}

#define GLD(srcp, dstp)                                               \
  __builtin_amdgcn_global_load_lds(                                   \
      (const __attribute__((address_space(1))) void*)(srcp),          \
      (__attribute__((address_space(3))) void*)(dstp), 16, 0, 0)

// ---------------- convw1: W1[:, :3072] -> bf16 ----------------
__global__ void convw1_kernel(const float* __restrict__ W1, unsigned short* __restrict__ W1a) {
  int id = blockIdx.x * 256 + threadIdx.x;      // fx4 id, 1024*768 total
  int d = id / 768, fi = id - d * 768;
  fx4 v = ((const fx4*)W1)[d * 1024 + fi];
  uv4 r; r[0] = f2bf(v[0]); r[1] = f2bf(v[1]); r[2] = f2bf(v[2]); r[3] = f2bf(v[3]);
  ((uv4*)W1a)[d * 768 + fi] = r;
}

// ---------------- convenc: enc fp32 -> bf16 (12,582,912 ui4 total) --------
__global__ void convenc_kernel(const float* __restrict__ enc, unsigned short* __restrict__ ebf) {
  int id = blockIdx.x * 256 + threadIdx.x;      // ui4 id, 12582912 total
  fx4 a = ((const fx4*)enc)[2 * id];
  fx4 b = ((const fx4*)enc)[2 * id + 1];
  ((ui4*)ebf)[id] = pack8(a, b);
}

// ---------------- hbias: hb[b,d] = hs·W1[d,3072:] + b1 ----------------
__global__ void hbias_kernel(const float* __restrict__ hs, const float* __restrict__ W1,
                             const float* __restrict__ b1, float* __restrict__ hb) {
  int idx = (blockIdx.x << 2) + (threadIdx.x >> 6);
  int lane = threadIdx.x & 63;
  int b = idx >> 10, d = idx & 1023;
  const fx4* hv = (const fx4*)hs;
  const fx4* wv = (const fx4*)W1;
  float s = 0.f;
#pragma unroll
  for (int i = 0; i < 4; ++i) {
    int k4 = lane + (i << 6);
    fx4 h = hv[(b << 8) + k4];
    fx4 w = wv[d * 1024 + 768 + k4];
    s += h[0] * w[0] + h[1] * w[1] + h[2] * w[2] + h[3] * w[3];
  }
#pragma unroll
  for (int off = 32; off; off >>= 1) s += __shfl_xor(s, off);
  if (lane == 0) hb[idx] = s + b1[d];
}

// ---------------- gemm8: m201-style, gload both operands ----------------
// M=32768, N=1024, K=3072. 48 K-tiles of BK=64. 8 waves (2Mx4N), wave
// 128x64 (acc 8x4). LDS: A 3x32KB (tri-buf) + B 2x32KB (dbuf) = 160KB.
// Per tile (4 phases of 16 MFMA): P1{issue Bh0(kt+1)} P2{issue Bh1(kt+1)}
// P3{issue Ah0(kt+2)} P4{issue Ah1(kt+2); vmcnt(4)}. vmcnt(4) at kt
// certifies A(kt+1)+B(kt+1), leaves A(kt+2) in flight. Buf legality:
// B(kt+1) target held B(kt-1) (reads done end kt-1); A(kt+2) held A(kt-1).
__global__ __launch_bounds__(512, 2)
void gemm8(const unsigned short* __restrict__ Ag,    // enc_bf [32768][3072]
           const unsigned short* __restrict__ Bg,    // W1a    [1024][3072]
           const float* __restrict__ hb,
           const float* __restrict__ w2,
           float* __restrict__ pe) {
  __shared__ __align__(16) unsigned short Ab[3][16384];   // [256 rows][64k]
  __shared__ __align__(16) unsigned short Bb[2][16384];   // [256 cols][64k]

  const int t = threadIdx.x, lane = t & 63, wid = t >> 6;
  const int wm = wid >> 2, wn = wid & 3;          // 2M x 4N waves

  // XCD-bijective swizzle: 512 blocks, XCD x owns lg [x*64, +64)
  const int bid = blockIdx.x;
  const int lg = ((bid & 7) << 6) | (bid >> 3);
  const int mt = lg >> 2, nt = lg & 3;
  const int row0 = mt << 8, col0 = nt << 8;

  // staging: wave wid covers rows/cols wid*32..+31; 4 loads (g=0..3) per
  // tile per operand; dest linear (base + lane*16B); source k-chunk
  // pre-swizzled c = (l&7)^(l>>3) (row&7 == l>>3 since bases are %8==0).
  const int l3 = lane >> 3, l7 = lane & 7;
  const unsigned short* asrc = Ag + (size_t)(row0 + wid * 32 + l3) * 3072 + ((l7 ^ l3) << 3);
  const unsigned short* bsrc = Bg + (size_t)(col0 + wid * 32 + l3) * 3072 + ((l7 ^ l3) << 3);
  const int dstb = wid << 11;                     // (wid*32 rows) * 64 elems

  // fragment reads: row r, chunk c -> elem r*64 + ((c ^ (r&7))<<3)
  const int r15 = lane & 15, qv = lane >> 4;
  const int aB = (wm * 128 + r15) << 6;
  const int bB = (wn * 64 + r15) << 6;
  const int s0 = (qv ^ (r15 & 7)) << 3;           // kh0 (chunks 0-3)
  const int s1 = ((qv + 4) ^ (r15 & 7)) << 3;     // kh1 (chunks 4-7)

  fx4 acc[8][4] = {};
  sv8 bfv[4];

#define ST_B(BN, kt, g) GLD(bsrc + (g) * 24576 + (kt) * 64, &Bb[BN][dstb + ((g) << 9)])
#define ST_A(AN, kt, g) GLD(asrc + (g) * 24576 + (kt) * 64, &Ab[AN][dstb + ((g) << 9)])

#define PHASE(AB, BBUF, MH, KH, ISSUE)                                \
  { sv8 af[4];                                                        \
    const int sx = (KH) ? s1 : s0;                                    \
    _Pragma("unroll")                                                 \
    for (int mi = 0; mi < 4; ++mi)                                    \
      af[mi] = *(const sv8*)&Ab[AB][aB + (((MH) * 64 + mi * 16) << 6) + sx]; \
    if ((MH) == 0) {                                                  \
      _Pragma("unroll")                                               \
      for (int ni = 0; ni < 4; ++ni)                                  \
        bfv[ni] = *(const sv8*)&Bb[BBUF][bB + ((ni * 16) << 6) + sx]; \
    }                                                                 \
    ISSUE                                                             \
    __builtin_amdgcn_s_barrier();                                     \
    asm volatile("s_waitcnt lgkmcnt(0)" ::: "memory");                \
    __builtin_amdgcn_s_setprio(1);                                    \
    _Pragma("unroll")                                                 \
    for (int mi = 0; mi < 4; ++mi)                                    \
      _Pragma("unroll")                                               \
      for (int ni = 0; ni < 4; ++ni)                                  \
        acc[(MH) * 4 + mi][ni] = __builtin_amdgcn_mfma_f32_16x16x32_bf16( \
            af[mi], bfv[ni], acc[(MH) * 4 + mi][ni], 0, 0, 0);        \
    __builtin_amdgcn_s_setprio(0);                                    \
  }

#define TILE(kt, AB, BBUF, BN, AN)                                    \
  PHASE(AB, BBUF, 0, 0, { if ((kt) < 47) { ST_B(BN, (kt) + 1, 0); ST_B(BN, (kt) + 1, 1); } }) \
  __builtin_amdgcn_s_barrier();                                       \
  PHASE(AB, BBUF, 1, 0, { if ((kt) < 47) { ST_B(BN, (kt) + 1, 2); ST_B(BN, (kt) + 1, 3); } }) \
  __builtin_amdgcn_s_barrier();                                       \
  PHASE(AB, BBUF, 0, 1, { if ((kt) < 46) { ST_A(AN, (kt) + 2, 0); ST_A(AN, (kt) + 2, 1); } }) \
  __builtin_amdgcn_s_barrier();                                       \
  PHASE(AB, BBUF, 1, 1, { if ((kt) < 46) { ST_A(AN, (kt) + 2, 2); ST_A(AN, (kt) + 2, 3); } }) \
  if ((kt) < 46)       { asm volatile("s_waitcnt vmcnt(4)" ::: "memory"); } \
  else if ((kt) == 46) { asm volatile("s_waitcnt vmcnt(0)" ::: "memory"); } \
  __builtin_amdgcn_s_barrier();

  // ---- prologue: B(0)->Bb0, A(0)->Ab0, A(1)->Ab1; leave A(1) in flight ----
  ST_B(0, 0, 0); ST_B(0, 0, 1); ST_B(0, 0, 2); ST_B(0, 0, 3);
  ST_A(0, 0, 0); ST_A(0, 0, 1); ST_A(0, 0, 2); ST_A(0, 0, 3);
  ST_A(1, 1, 0); ST_A(1, 1, 1); ST_A(1, 1, 2); ST_A(1, 1, 3);
  asm volatile("s_waitcnt vmcnt(4)" ::: "memory");   // B(0), A(0) landed
  __builtin_amdgcn_s_barrier();

  // ---- main loop: 48 tiles, period-6 buffer rotation (A %3, B %2) ----
  for (int it = 0; it < 8; ++it) {
    const int k6 = it * 6;
    TILE(k6 + 0, 0, 0, 1, 2)
    TILE(k6 + 1, 1, 1, 0, 0)
    TILE(k6 + 2, 2, 0, 1, 1)
    TILE(k6 + 3, 0, 1, 0, 2)
    TILE(k6 + 4, 1, 0, 1, 0)
    TILE(k6 + 5, 2, 1, 0, 1)
  }

  // ---- epilogue: p[row] += sum_cols tanh(acc + hb) * w2 ----
  // C layout: col = lane&15, row = (lane>>4)*4 + j
  const int b = row0 >> 10;
  float w2v[4], hbv[4];
#pragma unroll
  for (int ni = 0; ni < 4; ++ni) {
    int c = col0 + wn * 64 + ni * 16 + r15;
    w2v[ni] = w2[c];
    hbv[ni] = hb[(b << 10) + c];
  }
#pragma unroll
  for (int mi = 0; mi < 8; ++mi) {
#pragma unroll
    for (int j = 0; j < 4; ++j) {
      float pz = 0.f;
#pragma unroll
      for (int ni = 0; ni < 4; ++ni)
        pz += tanhf(acc[mi][ni][j] + hbv[ni]) * w2v[ni];
      pz += __shfl_xor(pz, 1); pz += __shfl_xor(pz, 2);
      pz += __shfl_xor(pz, 4); pz += __shfl_xor(pz, 8);
      if (r15 == 0) {
        int row = row0 + wm * 128 + mi * 16 + (qv << 2) + j;
        pe[(row << 4) + (nt << 2) + wn] = pz;
      }
    }
  }
#undef ST_A
#undef ST_B
#undef PHASE
#undef TILE
}

// ---------------- fallback gemm (R9, reg-staged 2-phase) ----------------
__global__ __launch_bounds__(512, 2)
void gemm2(const float* __restrict__ enc,
           const unsigned short* __restrict__ W1a,
           const float* __restrict__ hb,
           const float* __restrict__ w2,
           float* __restrict__ pe) {
  __shared__ __align__(16) unsigned short As[2][10240];
  __shared__ __align__(16) unsigned short Bs[2][8192];
  const int t = threadIdx.x;
  const int lane = t & 63, wid = t >> 6;
  const int wm = wid >> 2, wn = wid & 3;
  const int bid = blockIdx.x;
  const int lg = ((bid & 7) << 6) | (bid >> 3);
  const int mt = lg >> 2, ntile = lg & 3;
  const int row0 = mt << 8;
  const int col0 = ntile << 8;
  const fx4* encv = (const fx4*)enc;
  const int ar = t >> 1, ah = t & 1;
  const int agb = (row0 + ar) * 768 + ah * 4;
  const int awb = ar * 40 + ah * 16;
  const int l3 = lane >> 3, l7 = lane & 7;
  const int pre = l7 ^ l3;
  const unsigned short* bsrc0 =
      W1a + (size_t)(col0 + wid * 32 + 2 * l3 + (pre >> 2)) * 3072 + (pre & 3) * 8;
  const unsigned short* bsrc1 = bsrc0 + (size_t)16 * 3072;
  const int bdst0 = (wid * 16) * 64;
  const int bdst1 = (wid * 16 + 8) * 64;
  const int r15 = lane & 15, qv = lane >> 4;
  const int aro = (wm * 128 + r15) * 40 + qv * 8;
  const int cb = wn * 64 + r15;
  const int bro = (cb >> 1) * 64 + (((((cb & 1) << 2) + qv) ^ ((cb >> 1) & 7)) << 3);
  fx4 acc[8][4] = {};
  fx4 pa[2][4];
#define A_LOAD(s, kt) { _Pragma("unroll") for (int j = 0; j < 4; ++j) pa[s][j] = encv[agb + (kt) * 8 + j]; }
#define A_WRITE(s, buf) { *(ui4*)&As[buf][awb] = pack8(pa[s][0], pa[s][1]); \
                          *(ui4*)&As[buf][awb + 8] = pack8(pa[s][2], pa[s][3]); }
#define B_ISSUE(buf, kt) { GLD(bsrc0 + (kt) * 32, &Bs[buf][bdst0]); \
                           GLD(bsrc1 + (kt) * 32, &Bs[buf][bdst1]); }
#define COMPUTE(p)                                                    \
  { sv8 af[8], bfv[4];                                                \
    _Pragma("unroll")                                                 \
    for (int mi = 0; mi < 8; ++mi) af[mi] = *(const sv8*)&As[p][aro + mi * 640]; \
    _Pragma("unroll")                                                 \
    for (int ni = 0; ni < 4; ++ni) bfv[ni] = *(const sv8*)&Bs[p][bro + ni * 512]; \
    _Pragma("unroll")                                                 \
    for (int mi = 0; mi < 8; ++mi)                                    \
      _Pragma("unroll")                                               \
      for (int ni = 0; ni < 4; ++ni)                                  \
        acc[mi][ni] = __builtin_amdgcn_mfma_f32_16x16x32_bf16(af[mi], bfv[ni], acc[mi][ni], 0, 0, 0); }
#define ITER(kt, p)                                                   \
  { COMPUTE(p)                                                        \
    if ((kt) < 95) { A_WRITE(p ^ 1, p ^ 1) }                          \
    if ((kt) < 93) { A_LOAD(p ^ 1, (kt) + 3) }                        \
    __builtin_amdgcn_s_barrier();                                     \
    if ((kt) < 94) {                                                  \
      B_ISSUE(p, (kt) + 2)                                            \
      asm volatile("s_waitcnt vmcnt(6)" ::: "memory");                \
    } else if ((kt) == 94) {                                          \
      asm volatile("s_waitcnt vmcnt(0)" ::: "memory");                \
    }                                                                 \
    asm volatile("s_waitcnt lgkmcnt(0)" ::: "memory");                \
    __builtin_amdgcn_s_barrier(); }
  A_LOAD(0, 0)
  A_LOAD(1, 1)
  B_ISSUE(0, 0)
  A_WRITE(0, 0)
  B_ISSUE(1, 1)
  A_LOAD(0, 2)
  asm volatile("s_waitcnt vmcnt(6)" ::: "memory");
  asm volatile("s_waitcnt lgkmcnt(0)" ::: "memory");
  __builtin_amdgcn_s_barrier();
  for (int kt2 = 0; kt2 < 48; ++kt2) {
    const int kt = kt2 * 2;
    ITER(kt, 0)
    ITER(kt + 1, 1)
  }
  const int b = row0 >> 10;
  float w2v[4], hbv[4];
#pragma unroll
  for (int ni = 0; ni < 4; ++ni) {
    int c = col0 + wn * 64 + ni * 16 + r15;
    w2v[ni] = w2[c];
    hbv[ni] = hb[(b << 10) + c];
  }
#pragma unroll
  for (int mi = 0; mi < 8; ++mi) {
#pragma unroll
    for (int j = 0; j < 4; ++j) {
      float pz = 0.f;
#pragma unroll
      for (int ni = 0; ni < 4; ++ni)
        pz += tanhf(acc[mi][ni][j] + hbv[ni]) * w2v[ni];
      pz += __shfl_xor(pz, 1); pz += __shfl_xor(pz, 2);
      pz += __shfl_xor(pz, 4); pz += __shfl_xor(pz, 8);
      if (r15 == 0) {
        int row = row0 + wm * 128 + mi * 16 + (qv << 2) + j;
        pe[(row << 4) + (ntile << 2) + wn] = pz;
      }
    }
  }
#undef A_LOAD
#undef A_WRITE
#undef B_ISSUE
#undef COMPUTE
#undef ITER
}

// ---------------- softmax over S per batch ----------------
__global__ void softmax_kernel(const float* __restrict__ pe, float* __restrict__ alpha) {
  int b = blockIdx.x, t = threadIdx.x;
  int lane = t & 63, wid = t >> 6;
  float ev[4];
#pragma unroll
  for (int r = 0; r < 4; ++r) {
    int s = t + r * 256;
    const float* p = pe + ((b << 10) + s) * 16;
    float sum = 0.f;
#pragma unroll
    for (int i = 0; i < 16; ++i) sum += p[i];
    ev[r] = sum;
  }
  float m = fmaxf(fmaxf(ev[0], ev[1]), fmaxf(ev[2], ev[3]));
#pragma unroll
  for (int off = 32; off; off >>= 1) m = fmaxf(m, __shfl_xor(m, off));
  __shared__ float red[8];
  if (lane == 0) red[wid] = m;
  __syncthreads();
  m = fmaxf(fmaxf(red[0], red[1]), fmaxf(red[2], red[3]));
  float p4[4], ls = 0.f;
#pragma unroll
  for (int r = 0; r < 4; ++r) { p4[r] = expf(ev[r] - m); ls += p4[r]; }
#pragma unroll
  for (int off = 32; off; off >>= 1) ls += __shfl_xor(ls, off);
  if (lane == 0) red[4 + wid] = ls;
  __syncthreads();
  float inv = 1.0f / (red[4] + red[5] + red[6] + red[7]);
#pragma unroll
  for (int r = 0; r < 4; ++r) alpha[(b << 10) + t + r * 256] = p4[r] * inv;
}

// ---------------- ctxpart (bf16 enc), 384 threads ----------------
__global__ void ctxpart_bf_kernel(const unsigned short* __restrict__ ebf,
                                  const float* __restrict__ alpha,
                                  float* __restrict__ part) {
  int bid = blockIdx.x, b = bid >> 4, sc = bid & 15;
  int t = threadIdx.x;            // 0..383
  __shared__ float sal[64];
  if (t < 64) sal[t] = alpha[(b << 10) + (sc << 6) + t];
  __syncthreads();
  const ui4* ev = (const ui4*)ebf;            // 384 ui4 per row
  float a8[8] = {};
  int base = ((b << 10) + (sc << 6)) * 384;
  for (int si = 0; si < 64; ++si) {
    float a = sal[si];
    ui4 v = ev[base + si * 384 + t];
#pragma unroll
    for (int j = 0; j < 4; ++j) {
      unsigned u = v[j];
      a8[2 * j]     += a * __uint_as_float(u << 16);
      a8[2 * j + 1] += a * __uint_as_float(u & 0xFFFF0000u);
    }
  }
  fx4* pp = (fx4*)part;
  int pb = ((b << 4) + sc) * 768 + t * 2;
  fx4 o0 = {a8[0], a8[1], a8[2], a8[3]};
  fx4 o1 = {a8[4], a8[5], a8[6], a8[7]};
  pp[pb] = o0; pp[pb + 1] = o1;
}

// ---------------- ctxpart (fp32 enc, fallback) ----------------
__global__ void ctxpart_kernel(const float* __restrict__ enc, const float* __restrict__ alpha,
                               float* __restrict__ part) {
  int bid = blockIdx.x, b = bid >> 4, sc = bid & 15;
  int t = threadIdx.x;
  __shared__ float sal[64];
  if (t < 64) sal[t] = alpha[(b << 10) + (sc << 6) + t];
  __syncthreads();
  const fx4* ev = (const fx4*)enc;
  fx4 a0 = {}, a1 = {}, a2 = {};
  int base = ((b << 10) + (sc << 6)) * 768;
  for (int si = 0; si < 64; ++si) {
    float a = sal[si];
    const fx4* rp = ev + base + si * 768;
    a0 += a * rp[t];
    a1 += a * rp[256 + t];
    a2 += a * rp[512 + t];
  }
  fx4* pp = (fx4*)part;
  int pb = ((b << 4) + sc) * 768;
  pp[pb + t] = a0; pp[pb + 256 + t] = a1; pp[pb + 512 + t] = a2;
}

__global__ void ctxreduce_kernel(const float* __restrict__ part, float* __restrict__ ctx) {
  int j = blockIdx.x * 256 + threadIdx.x;     // 0..24575 fx4
  int b = j / 768, fi = j - b * 768;
  const fx4* pp = (const fx4*)part;
  fx4 s = {};
#pragma unroll
  for (int i = 0; i < 16; ++i) s += pp[((b << 4) + i) * 768 + fi];
  ((fx4*)ctx)[b * 768 + fi] = s;
}

// ---------------- final: out = ctx·W3^T + b3 ----------------
__global__ void final_kernel(const float* __restrict__ ctx, const float* __restrict__ W3,
                             const float* __restrict__ b3, float* __restrict__ out) {
  int idx = (blockIdx.x << 2) + (threadIdx.x >> 6);
  int lane = threadIdx.x & 63;
  int b = idx >> 10, d = idx & 1023;
  const fx4* cv = (const fx4*)ctx;
  const fx4* wv = (const fx4*)W3;
  float s = 0.f;
#pragma unroll
  for (int i = 0; i < 12; ++i) {
    int f4 = lane + (i << 6);
    fx4 c = cv[b * 768 + f4];
    fx4 w = wv[d * 768 + f4];
    s += c[0] * w[0] + c[1] * w[1] + c[2] * w[2] + c[3] * w[3];
  }
#pragma unroll
  for (int off = 32; off; off >>= 1) s += __shfl_xor(s, off);
  if (lane == 0) out[idx] = s + b3[d];
}

extern "C" void kernel_launch(void* const* d_in, const int* in_sizes, int n_in,
                              void* d_out, int out_size, void* d_ws, size_t ws_size,
                              hipStream_t stream) {
  const float* hs  = (const float*)d_in[0];   // (32, 1024)
  const float* enc = (const float*)d_in[1];   // (32, 1024, 3072)
  const float* W1  = (const float*)d_in[2];   // (1024, 4096)
  const float* b1  = (const float*)d_in[3];   // (1024)
  const float* w2  = (const float*)d_in[4];   // (1, 1024)
  const float* W3  = (const float*)d_in[5];   // (1024, 3072)
  const float* b3  = (const float*)d_in[6];   // (1024)
  float* out = (float*)d_out;
  char* ws = (char*)d_ws;

  const size_t NEED_A = 216662016ULL;   // enc_bf path

  if (ws_size >= NEED_A) {
    // PATH A layout
    unsigned short* ebf = (unsigned short*)(ws);             // 201,326,592 B
    unsigned short* W1a = (unsigned short*)(ws + 201326592); //   6,291,456 B
    float* pe    = (float*)(ws + 207618048);                 //   2,097,152 B
    float* alpha = (float*)(ws + 209715200);                 //     131,072 B
    float* hb    = (float*)(ws + 209846272);                 //     131,072 B
    float* ctx   = (float*)(ws + 209977344);                 //     393,216 B
    float* part  = (float*)(ws + 210370560);                 //   6,291,456 B

    convw1_kernel<<<3072, 256, 0, stream>>>(W1, W1a);
    convenc_kernel<<<49152, 256, 0, stream>>>(enc, ebf);     // FIXED grid
    hbias_kernel<<<8192, 256, 0, stream>>>(hs, W1, b1, hb);
    gemm8<<<512, 512, 0, stream>>>(ebf, W1a, hb, w2, pe);
    softmax_kernel<<<32, 256, 0, stream>>>(pe, alpha);
    ctxpart_bf_kernel<<<512, 384, 0, stream>>>(ebf, alpha, part);
    ctxreduce_kernel<<<96, 256, 0, stream>>>(part, ctx);
    final_kernel<<<8192, 256, 0, stream>>>(ctx, W3, b3, out);
  } else {
    // PATH B (R9 fallback) layout
    unsigned short* W1a = (unsigned short*)(ws);             // 6,291,456 B
    float* pe    = (float*)(ws + 6291456);                   // 2,097,152 B
    float* alpha = (float*)(ws + 8388608);                   //   131,072 B
    float* hb    = (float*)(ws + 8519680);                   //   131,072 B
    float* ctx   = (float*)(ws + 8650752);                   //   393,216 B
    float* part  = (float*)(ws + 9043968);                   // 6,291,456 B

    convw1_kernel<<<3072, 256, 0, stream>>>(W1, W1a);
    hbias_kernel<<<8192, 256, 0, stream>>>(hs, W1, b1, hb);
    gemm2<<<512, 512, 0, stream>>>(enc, W1a, hb, w2, pe);
    softmax_kernel<<<32, 256, 0, stream>>>(pe, alpha);
    ctxpart_kernel<<<512, 256, 0, stream>>>(enc, alpha, part);
    ctxreduce_kernel<<<96, 256, 0, stream>>>(part, ctx);
    final_kernel<<<8192, 256, 0, stream>>>(ctx, W3, b3, out);
  }
}

// Round 12
// 409.995 us; speedup vs baseline: 1.0873x; 1.0873x over previous
//
#include <hip/hip_runtime.h>
#include <hip/hip_bf16.h>

// Attention_aux: fused aux-attention scorer + context + output projection.
// PATH A (ws >= 216.7 MB):
//   convw1 (W1->bf16), convenc (enc->bf16, 201MB, grid 49152), hbias,
//   gemm8: 256x256 BK=64 GEMM, gload_lds BOTH operands, A tri-buf + B dbuf
//          (160KB LDS), 4 quadrant clusters of 16 MFMA per K-tile,
//          NO intra-tile barriers (same-buffer reads; compiler's fine
//          lgkmcnt overlaps ds_read with MFMA), counted vmcnt(4) + ONE
//          barrier per tile, setprio, 0-conflict XOR-8 LDS geometry.
//   softmax, ctxpart_bf (bf16 enc), ctxreduce, final.
// PATH B (fallback, small ws): R9 pipeline verbatim.

typedef float          fx4 __attribute__((ext_vector_type(4)));
typedef short          sv8 __attribute__((ext_vector_type(8)));
typedef unsigned short uv4 __attribute__((ext_vector_type(4)));
typedef unsigned int   ui4 __attribute__((ext_vector_type(4)));

__device__ __forceinline__ unsigned short f2bf(float x) {
  unsigned u = __float_as_uint(x);
  return (unsigned short)((u + 0x7FFFu + ((u >> 16) & 1u)) >> 16);
}
__device__ __forceinline__ unsigned cvtpk(float lo, float hi) {
  unsigned r;
  asm("v_cvt_pk_bf16_f32 %0, %1, %2" : "=v"(r) : "v"(lo), "v"(hi));
  return r;
}
__device__ __forceinline__ ui4 pack8(fx4 a, fx4 b) {
  ui4 v;
  v[0] = cvtpk(a[0], a[1]); v[1] = cvtpk(a[2], a[3]);
  v[2] = cvtpk(b[0], b[1]); v[3] = cvtpk(b[2], b[3]);
  return v;
}

#define GLD(srcp, dstp)                                               \
  __builtin_amdgcn_global_load_lds(                                   \
      (const __attribute__((address_space(1))) void*)(srcp),          \
      (__attribute__((address_space(3))) void*)(dstp), 16, 0, 0)

// ---------------- convw1: W1[:, :3072] -> bf16 ----------------
__global__ void convw1_kernel(const float* __restrict__ W1, unsigned short* __restrict__ W1a) {
  int id = blockIdx.x * 256 + threadIdx.x;      // fx4 id, 1024*768 total
  int d = id / 768, fi = id - d * 768;
  fx4 v = ((const fx4*)W1)[d * 1024 + fi];
  uv4 r; r[0] = f2bf(v[0]); r[1] = f2bf(v[1]); r[2] = f2bf(v[2]); r[3] = f2bf(v[3]);
  ((uv4*)W1a)[d * 768 + fi] = r;
}

// ---------------- convenc: enc fp32 -> bf16 (12,582,912 ui4 total) --------
__global__ void convenc_kernel(const float* __restrict__ enc, unsigned short* __restrict__ ebf) {
  int id = blockIdx.x * 256 + threadIdx.x;      // ui4 id
  fx4 a = ((const fx4*)enc)[2 * id];
  fx4 b = ((const fx4*)enc)[2 * id + 1];
  ((ui4*)ebf)[id] = pack8(a, b);
}

// ---------------- hbias: hb[b,d] = hs·W1[d,3072:] + b1 ----------------
__global__ void hbias_kernel(const float* __restrict__ hs, const float* __restrict__ W1,
                             const float* __restrict__ b1, float* __restrict__ hb) {
  int idx = (blockIdx.x << 2) + (threadIdx.x >> 6);
  int lane = threadIdx.x & 63;
  int b = idx >> 10, d = idx & 1023;
  const fx4* hv = (const fx4*)hs;
  const fx4* wv = (const fx4*)W1;
  float s = 0.f;
#pragma unroll
  for (int i = 0; i < 4; ++i) {
    int k4 = lane + (i << 6);
    fx4 h = hv[(b << 8) + k4];
    fx4 w = wv[d * 1024 + 768 + k4];
    s += h[0] * w[0] + h[1] * w[1] + h[2] * w[2] + h[3] * w[3];
  }
#pragma unroll
  for (int off = 32; off; off >>= 1) s += __shfl_xor(s, off);
  if (lane == 0) hb[idx] = s + b1[d];
}

// ---------------- gemm8: gload both operands, 1 barrier/tile ----------------
// M=32768, N=1024, K=3072. 48 K-tiles of BK=64. 8 waves (2Mx4N), wave
// 128x64 (acc 8x4). LDS: A 3x32KB + B 2x32KB = 160KB.
// Per tile: 4 quadrant clusters {frag ds_reads; gload issues; 16 MFMA}
// with NO internal barriers (all quadrants read the same tile buffers;
// compiler overlaps reads with MFMA via fine lgkmcnt). Tile end:
// vmcnt(4) retires A(kt+1)+B(kt+1), leaves A(kt+2):4 in flight; ONE
// s_barrier = write-after-read fence for next tile's gload targets.
__global__ __launch_bounds__(512, 2)
void gemm8(const unsigned short* __restrict__ Ag,    // enc_bf [32768][3072]
           const unsigned short* __restrict__ Bg,    // W1a    [1024][3072]
           const float* __restrict__ hb,
           const float* __restrict__ w2,
           float* __restrict__ pe) {
  __shared__ __align__(16) unsigned short Ab[3][16384];   // [256 rows][64k]
  __shared__ __align__(16) unsigned short Bb[2][16384];   // [256 cols][64k]

  const int t = threadIdx.x, lane = t & 63, wid = t >> 6;
  const int wm = wid >> 2, wn = wid & 3;          // 2M x 4N waves

  // XCD-bijective swizzle: 512 blocks, XCD x owns lg [x*64, +64)
  const int bid = blockIdx.x;
  const int lg = ((bid & 7) << 6) | (bid >> 3);
  const int mt = lg >> 2, nt = lg & 3;
  const int row0 = mt << 8, col0 = nt << 8;

  // staging: wave wid covers rows/cols wid*32..+31; dest linear
  // (base + lane*16B); source k-chunk pre-swizzled c = (l&7)^(l>>3).
  const int l3 = lane >> 3, l7 = lane & 7;
  const unsigned short* asrc = Ag + (size_t)(row0 + wid * 32 + l3) * 3072 + ((l7 ^ l3) << 3);
  const unsigned short* bsrc = Bg + (size_t)(col0 + wid * 32 + l3) * 3072 + ((l7 ^ l3) << 3);
  const int dstb = wid << 11;                     // (wid*32 rows) * 64 elems

  // fragment reads: row r, chunk c -> elem r*64 + ((c ^ (r&7))<<3)
  const int r15 = lane & 15, qv = lane >> 4;
  const int aB = (wm * 128 + r15) << 6;
  const int bB = (wn * 64 + r15) << 6;
  const int s0 = (qv ^ (r15 & 7)) << 3;           // kh0 (chunks 0-3)
  const int s1 = ((qv + 4) ^ (r15 & 7)) << 3;     // kh1 (chunks 4-7)

  fx4 acc[8][4] = {};
  sv8 bfv[4];

#define ST_B(BN, kt, g) GLD(bsrc + (g) * 24576 + (kt) * 64, &Bb[BN][dstb + ((g) << 9)])
#define ST_A(AN, kt, g) GLD(asrc + (g) * 24576 + (kt) * 64, &Ab[AN][dstb + ((g) << 9)])

// quadrant cluster: frag reads + stage issues + 16 MFMA, no barriers
#define PHASE(AB, BBUF, MH, KH, ISSUE)                                \
  { sv8 af[4];                                                        \
    const int sx = (KH) ? s1 : s0;                                    \
    _Pragma("unroll")                                                 \
    for (int mi = 0; mi < 4; ++mi)                                    \
      af[mi] = *(const sv8*)&Ab[AB][aB + (((MH) * 64 + mi * 16) << 6) + sx]; \
    if ((MH) == 0) {                                                  \
      _Pragma("unroll")                                               \
      for (int ni = 0; ni < 4; ++ni)                                  \
        bfv[ni] = *(const sv8*)&Bb[BBUF][bB + ((ni * 16) << 6) + sx]; \
    }                                                                 \
    ISSUE                                                             \
    __builtin_amdgcn_s_setprio(1);                                    \
    _Pragma("unroll")                                                 \
    for (int mi = 0; mi < 4; ++mi)                                    \
      _Pragma("unroll")                                               \
      for (int ni = 0; ni < 4; ++ni)                                  \
        acc[(MH) * 4 + mi][ni] = __builtin_amdgcn_mfma_f32_16x16x32_bf16( \
            af[mi], bfv[ni], acc[(MH) * 4 + mi][ni], 0, 0, 0);        \
    __builtin_amdgcn_s_setprio(0);                                    \
  }

#define TILE(kt, AB, BBUF, BN, AN)                                    \
  PHASE(AB, BBUF, 0, 0, { if ((kt) < 47) { ST_B(BN, (kt) + 1, 0); ST_B(BN, (kt) + 1, 1); } }) \
  PHASE(AB, BBUF, 1, 0, { if ((kt) < 47) { ST_B(BN, (kt) + 1, 2); ST_B(BN, (kt) + 1, 3); } }) \
  PHASE(AB, BBUF, 0, 1, { if ((kt) < 46) { ST_A(AN, (kt) + 2, 0); ST_A(AN, (kt) + 2, 1); } }) \
  PHASE(AB, BBUF, 1, 1, { if ((kt) < 46) { ST_A(AN, (kt) + 2, 2); ST_A(AN, (kt) + 2, 3); } }) \
  if ((kt) < 46)       { asm volatile("s_waitcnt vmcnt(4)" ::: "memory"); } \
  else if ((kt) == 46) { asm volatile("s_waitcnt vmcnt(0)" ::: "memory"); } \
  __builtin_amdgcn_s_barrier();

  // ---- prologue: B(0)->Bb0, A(0)->Ab0, A(1)->Ab1; leave A(1) in flight ----
  ST_B(0, 0, 0); ST_B(0, 0, 1); ST_B(0, 0, 2); ST_B(0, 0, 3);
  ST_A(0, 0, 0); ST_A(0, 0, 1); ST_A(0, 0, 2); ST_A(0, 0, 3);
  ST_A(1, 1, 0); ST_A(1, 1, 1); ST_A(1, 1, 2); ST_A(1, 1, 3);
  asm volatile("s_waitcnt vmcnt(4)" ::: "memory");   // B(0), A(0) landed
  __builtin_amdgcn_s_barrier();

  // ---- main loop: 48 tiles, period-6 buffer rotation (A %3, B %2) ----
  for (int it = 0; it < 8; ++it) {
    const int k6 = it * 6;
    TILE(k6 + 0, 0, 0, 1, 2)
    TILE(k6 + 1, 1, 1, 0, 0)
    TILE(k6 + 2, 2, 0, 1, 1)
    TILE(k6 + 3, 0, 1, 0, 2)
    TILE(k6 + 4, 1, 0, 1, 0)
    TILE(k6 + 5, 2, 1, 0, 1)
  }

  // ---- epilogue: p[row] += sum_cols tanh(acc + hb) * w2 ----
  // C layout: col = lane&15, row = (lane>>4)*4 + j
  const int b = row0 >> 10;
  float w2v[4], hbv[4];
#pragma unroll
  for (int ni = 0; ni < 4; ++ni) {
    int c = col0 + wn * 64 + ni * 16 + r15;
    w2v[ni] = w2[c];
    hbv[ni] = hb[(b << 10) + c];
  }
#pragma unroll
  for (int mi = 0; mi < 8; ++mi) {
#pragma unroll
    for (int j = 0; j < 4; ++j) {
      float pz = 0.f;
#pragma unroll
      for (int ni = 0; ni < 4; ++ni)
        pz += tanhf(acc[mi][ni][j] + hbv[ni]) * w2v[ni];
      pz += __shfl_xor(pz, 1); pz += __shfl_xor(pz, 2);
      pz += __shfl_xor(pz, 4); pz += __shfl_xor(pz, 8);
      if (r15 == 0) {
        int row = row0 + wm * 128 + mi * 16 + (qv << 2) + j;
        pe[(row << 4) + (nt << 2) + wn] = pz;
      }
    }
  }
#undef ST_A
#undef ST_B
#undef PHASE
#undef TILE
}

// ---------------- fallback gemm (R9, reg-staged 2-phase) ----------------
__global__ __launch_bounds__(512, 2)
void gemm2(const float* __restrict__ enc,
           const unsigned short* __restrict__ W1a,
           const float* __restrict__ hb,
           const float* __restrict__ w2,
           float* __restrict__ pe) {
  __shared__ __align__(16) unsigned short As[2][10240];
  __shared__ __align__(16) unsigned short Bs[2][8192];
  const int t = threadIdx.x;
  const int lane = t & 63, wid = t >> 6;
  const int wm = wid >> 2, wn = wid & 3;
  const int bid = blockIdx.x;
  const int lg = ((bid & 7) << 6) | (bid >> 3);
  const int mt = lg >> 2, ntile = lg & 3;
  const int row0 = mt << 8;
  const int col0 = ntile << 8;
  const fx4* encv = (const fx4*)enc;
  const int ar = t >> 1, ah = t & 1;
  const int agb = (row0 + ar) * 768 + ah * 4;
  const int awb = ar * 40 + ah * 16;
  const int l3 = lane >> 3, l7 = lane & 7;
  const int pre = l7 ^ l3;
  const unsigned short* bsrc0 =
      W1a + (size_t)(col0 + wid * 32 + 2 * l3 + (pre >> 2)) * 3072 + (pre & 3) * 8;
  const unsigned short* bsrc1 = bsrc0 + (size_t)16 * 3072;
  const int bdst0 = (wid * 16) * 64;
  const int bdst1 = (wid * 16 + 8) * 64;
  const int r15 = lane & 15, qv = lane >> 4;
  const int aro = (wm * 128 + r15) * 40 + qv * 8;
  const int cb = wn * 64 + r15;
  const int bro = (cb >> 1) * 64 + (((((cb & 1) << 2) + qv) ^ ((cb >> 1) & 7)) << 3);
  fx4 acc[8][4] = {};
  fx4 pa[2][4];
#define A_LOAD(s, kt) { _Pragma("unroll") for (int j = 0; j < 4; ++j) pa[s][j] = encv[agb + (kt) * 8 + j]; }
#define A_WRITE(s, buf) { *(ui4*)&As[buf][awb] = pack8(pa[s][0], pa[s][1]); \
                          *(ui4*)&As[buf][awb + 8] = pack8(pa[s][2], pa[s][3]); }
#define B_ISSUE(buf, kt) { GLD(bsrc0 + (kt) * 32, &Bs[buf][bdst0]); \
                           GLD(bsrc1 + (kt) * 32, &Bs[buf][bdst1]); }
#define COMPUTE(p)                                                    \
  { sv8 af[8], bfv[4];                                                \
    _Pragma("unroll")                                                 \
    for (int mi = 0; mi < 8; ++mi) af[mi] = *(const sv8*)&As[p][aro + mi * 640]; \
    _Pragma("unroll")                                                 \
    for (int ni = 0; ni < 4; ++ni) bfv[ni] = *(const sv8*)&Bs[p][bro + ni * 512]; \
    _Pragma("unroll")                                                 \
    for (int mi = 0; mi < 8; ++mi)                                    \
      _Pragma("unroll")                                               \
      for (int ni = 0; ni < 4; ++ni)                                  \
        acc[mi][ni] = __builtin_amdgcn_mfma_f32_16x16x32_bf16(af[mi], bfv[ni], acc[mi][ni], 0, 0, 0); }
#define ITER(kt, p)                                                   \
  { COMPUTE(p)                                                        \
    if ((kt) < 95) { A_WRITE(p ^ 1, p ^ 1) }                          \
    if ((kt) < 93) { A_LOAD(p ^ 1, (kt) + 3) }                        \
    __builtin_amdgcn_s_barrier();                                     \
    if ((kt) < 94) {                                                  \
      B_ISSUE(p, (kt) + 2)                                            \
      asm volatile("s_waitcnt vmcnt(6)" ::: "memory");                \
    } else if ((kt) == 94) {                                          \
      asm volatile("s_waitcnt vmcnt(0)" ::: "memory");                \
    }                                                                 \
    asm volatile("s_waitcnt lgkmcnt(0)" ::: "memory");                \
    __builtin_amdgcn_s_barrier(); }
  A_LOAD(0, 0)
  A_LOAD(1, 1)
  B_ISSUE(0, 0)
  A_WRITE(0, 0)
  B_ISSUE(1, 1)
  A_LOAD(0, 2)
  asm volatile("s_waitcnt vmcnt(6)" ::: "memory");
  asm volatile("s_waitcnt lgkmcnt(0)" ::: "memory");
  __builtin_amdgcn_s_barrier();
  for (int kt2 = 0; kt2 < 48; ++kt2) {
    const int kt = kt2 * 2;
    ITER(kt, 0)
    ITER(kt + 1, 1)
  }
  const int b = row0 >> 10;
  float w2v[4], hbv[4];
#pragma unroll
  for (int ni = 0; ni < 4; ++ni) {
    int c = col0 + wn * 64 + ni * 16 + r15;
    w2v[ni] = w2[c];
    hbv[ni] = hb[(b << 10) + c];
  }
#pragma unroll
  for (int mi = 0; mi < 8; ++mi) {
#pragma unroll
    for (int j = 0; j < 4; ++j) {
      float pz = 0.f;
#pragma unroll
      for (int ni = 0; ni < 4; ++ni)
        pz += tanhf(acc[mi][ni][j] + hbv[ni]) * w2v[ni];
      pz += __shfl_xor(pz, 1); pz += __shfl_xor(pz, 2);
      pz += __shfl_xor(pz, 4); pz += __shfl_xor(pz, 8);
      if (r15 == 0) {
        int row = row0 + wm * 128 + mi * 16 + (qv << 2) + j;
        pe[(row << 4) + (ntile << 2) + wn] = pz;
      }
    }
  }
#undef A_LOAD
#undef A_WRITE
#undef B_ISSUE
#undef COMPUTE
#undef ITER
}

// ---------------- softmax over S per batch ----------------
__global__ void softmax_kernel(const float* __restrict__ pe, float* __restrict__ alpha) {
  int b = blockIdx.x, t = threadIdx.x;
  int lane = t & 63, wid = t >> 6;
  float ev[4];
#pragma unroll
  for (int r = 0; r < 4; ++r) {
    int s = t + r * 256;
    const float* p = pe + ((b << 10) + s) * 16;
    float sum = 0.f;
#pragma unroll
    for (int i = 0; i < 16; ++i) sum += p[i];
    ev[r] = sum;
  }
  float m = fmaxf(fmaxf(ev[0], ev[1]), fmaxf(ev[2], ev[3]));
#pragma unroll
  for (int off = 32; off; off >>= 1) m = fmaxf(m, __shfl_xor(m, off));
  __shared__ float red[8];
  if (lane == 0) red[wid] = m;
  __syncthreads();
  m = fmaxf(fmaxf(red[0], red[1]), fmaxf(red[2], red[3]));
  float p4[4], ls = 0.f;
#pragma unroll
  for (int r = 0; r < 4; ++r) { p4[r] = expf(ev[r] - m); ls += p4[r]; }
#pragma unroll
  for (int off = 32; off; off >>= 1) ls += __shfl_xor(ls, off);
  if (lane == 0) red[4 + wid] = ls;
  __syncthreads();
  float inv = 1.0f / (red[4] + red[5] + red[6] + red[7]);
#pragma unroll
  for (int r = 0; r < 4; ++r) alpha[(b << 10) + t + r * 256] = p4[r] * inv;
}

// ---------------- ctxpart (bf16 enc), 384 threads ----------------
__global__ void ctxpart_bf_kernel(const unsigned short* __restrict__ ebf,
                                  const float* __restrict__ alpha,
                                  float* __restrict__ part) {
  int bid = blockIdx.x, b = bid >> 4, sc = bid & 15;
  int t = threadIdx.x;            // 0..383
  __shared__ float sal[64];
  if (t < 64) sal[t] = alpha[(b << 10) + (sc << 6) + t];
  __syncthreads();
  const ui4* ev = (const ui4*)ebf;            // 384 ui4 per row
  float a8[8] = {};
  int base = ((b << 10) + (sc << 6)) * 384;
  for (int si = 0; si < 64; ++si) {
    float a = sal[si];
    ui4 v = ev[base + si * 384 + t];
#pragma unroll
    for (int j = 0; j < 4; ++j) {
      unsigned u = v[j];
      a8[2 * j]     += a * __uint_as_float(u << 16);
      a8[2 * j + 1] += a * __uint_as_float(u & 0xFFFF0000u);
    }
  }
  fx4* pp = (fx4*)part;
  int pb = ((b << 4) + sc) * 768 + t * 2;
  fx4 o0 = {a8[0], a8[1], a8[2], a8[3]};
  fx4 o1 = {a8[4], a8[5], a8[6], a8[7]};
  pp[pb] = o0; pp[pb + 1] = o1;
}

// ---------------- ctxpart (fp32 enc, fallback) ----------------
__global__ void ctxpart_kernel(const float* __restrict__ enc, const float* __restrict__ alpha,
                               float* __restrict__ part) {
  int bid = blockIdx.x, b = bid >> 4, sc = bid & 15;
  int t = threadIdx.x;
  __shared__ float sal[64];
  if (t < 64) sal[t] = alpha[(b << 10) + (sc << 6) + t];
  __syncthreads();
  const fx4* ev = (const fx4*)enc;
  fx4 a0 = {}, a1 = {}, a2 = {};
  int base = ((b << 10) + (sc << 6)) * 768;
  for (int si = 0; si < 64; ++si) {
    float a = sal[si];
    const fx4* rp = ev + base + si * 768;
    a0 += a * rp[t];
    a1 += a * rp[256 + t];
    a2 += a * rp[512 + t];
  }
  fx4* pp = (fx4*)part;
  int pb = ((b << 4) + sc) * 768;
  pp[pb + t] = a0; pp[pb + 256 + t] = a1; pp[pb + 512 + t] = a2;
}

__global__ void ctxreduce_kernel(const float* __restrict__ part, float* __restrict__ ctx) {
  int j = blockIdx.x * 256 + threadIdx.x;     // 0..24575 fx4
  int b = j / 768, fi = j - b * 768;
  const fx4* pp = (const fx4*)part;
  fx4 s = {};
#pragma unroll
  for (int i = 0; i < 16; ++i) s += pp[((b << 4) + i) * 768 + fi];
  ((fx4*)ctx)[b * 768 + fi] = s;
}

// ---------------- final: out = ctx·W3^T + b3 ----------------
__global__ void final_kernel(const float* __restrict__ ctx, const float* __restrict__ W3,
                             const float* __restrict__ b3, float* __restrict__ out) {
  int idx = (blockIdx.x << 2) + (threadIdx.x >> 6);
  int lane = threadIdx.x & 63;
  int b = idx >> 10, d = idx & 1023;
  const fx4* cv = (const fx4*)ctx;
  const fx4* wv = (const fx4*)W3;
  float s = 0.f;
#pragma unroll
  for (int i = 0; i < 12; ++i) {
    int f4 = lane + (i << 6);
    fx4 c = cv[b * 768 + f4];
    fx4 w = wv[d * 768 + f4];
    s += c[0] * w[0] + c[1] * w[1] + c[2] * w[2] + c[3] * w[3];
  }
#pragma unroll
  for (int off = 32; off; off >>= 1) s += __shfl_xor(s, off);
  if (lane == 0) out[idx] = s + b3[d];
}

extern "C" void kernel_launch(void* const* d_in, const int* in_sizes, int n_in,
                              void* d_out, int out_size, void* d_ws, size_t ws_size,
                              hipStream_t stream) {
  const float* hs  = (const float*)d_in[0];   // (32, 1024)
  const float* enc = (const float*)d_in[1];   // (32, 1024, 3072)
  const float* W1  = (const float*)d_in[2];   // (1024, 4096)
  const float* b1  = (const float*)d_in[3];   // (1024)
  const float* w2  = (const float*)d_in[4];   // (1, 1024)
  const float* W3  = (const float*)d_in[5];   // (1024, 3072)
  const float* b3  = (const float*)d_in[6];   // (1024)
  float* out = (float*)d_out;
  char* ws = (char*)d_ws;

  const size_t NEED_A = 216662016ULL;   // enc_bf path

  if (ws_size >= NEED_A) {
    // PATH A layout
    unsigned short* ebf = (unsigned short*)(ws);             // 201,326,592 B
    unsigned short* W1a = (unsigned short*)(ws + 201326592); //   6,291,456 B
    float* pe    = (float*)(ws + 207618048);                 //   2,097,152 B
    float* alpha = (float*)(ws + 209715200);                 //     131,072 B
    float* hb    = (float*)(ws + 209846272);                 //     131,072 B
    float* ctx   = (float*)(ws + 209977344);                 //     393,216 B
    float* part  = (float*)(ws + 210370560);                 //   6,291,456 B

    convw1_kernel<<<3072, 256, 0, stream>>>(W1, W1a);
    convenc_kernel<<<49152, 256, 0, stream>>>(enc, ebf);
    hbias_kernel<<<8192, 256, 0, stream>>>(hs, W1, b1, hb);
    gemm8<<<512, 512, 0, stream>>>(ebf, W1a, hb, w2, pe);
    softmax_kernel<<<32, 256, 0, stream>>>(pe, alpha);
    ctxpart_bf_kernel<<<512, 384, 0, stream>>>(ebf, alpha, part);
    ctxreduce_kernel<<<96, 256, 0, stream>>>(part, ctx);
    final_kernel<<<8192, 256, 0, stream>>>(ctx, W3, b3, out);
  } else {
    // PATH B (R9 fallback) layout
    unsigned short* W1a = (unsigned short*)(ws);             // 6,291,456 B
    float* pe    = (float*)(ws + 6291456);                   // 2,097,152 B
    float* alpha = (float*)(ws + 8388608);                   //   131,072 B
    float* hb    = (float*)(ws + 8519680);                   //   131,072 B
    float* ctx   = (float*)(ws + 8650752);                   //   393,216 B
    float* part  = (float*)(ws + 9043968);                   // 6,291,456 B

    convw1_kernel<<<3072, 256, 0, stream>>>(W1, W1a);
    hbias_kernel<<<8192, 256, 0, stream>>>(hs, W1, b1, hb);
    gemm2<<<512, 512, 0, stream>>>(enc, W1a, hb, w2, pe);
    softmax_kernel<<<32, 256, 0, stream>>>(pe, alpha);
    ctxpart_kernel<<<512, 256, 0, stream>>>(enc, alpha, part);
    ctxreduce_kernel<<<96, 256, 0, stream>>>(part, ctx);
    final_kernel<<<8192, 256, 0, stream>>>(ctx, W3, b3, out);
  }
}